// Round 14
// baseline (294.462 us; speedup 1.0000x reference)
//
#include <hip/hip_runtime.h>
#include <hip/hip_bf16.h>

#define DIM 1024
#define SEQ 4096
#define NB 4
#define MROWS (NB * SEQ)   // 16384
#define NC 64              // chunks per sequence
#define CL (SEQ / NC)      // 64 L-positions per chunk

// GEMM tiling: 256x256 tile, BK=32, 3 LDS slots (A fp32 32KB + B bf16 16KB each)
#define BM 256
#define BN 256
#define BK 32
#define NTK 32                   // K-tiles: 1024/32
#define SLOTB 49152              // 48 KB per slot
#define GEMM_LDS (3 * SLOTB)     // 144 KB -> exactly 1 block/CU
#define NBLK 256                 // grid size == CU count (residency by construction)

typedef __attribute__((ext_vector_type(8))) short bf16x8;
typedef __attribute__((ext_vector_type(4))) float f32x4;

static __device__ __forceinline__ unsigned short f2bf(float f) {
    union { float f; unsigned u; } v; v.f = f;
    unsigned r = v.u + 0x7FFF + ((v.u >> 16) & 1);
    return (unsigned short)(r >> 16);
}

// v_cvt_pk_bf16_f32: RNE, lo=bf16(a), hi=bf16(b)
static __device__ __forceinline__ unsigned cvtpk(float a, float b) {
    unsigned r;
    asm("v_cvt_pk_bf16_f32 %0, %1, %2" : "=v"(r) : "v"(a), "v"(b));
    return r;
}

static __device__ __forceinline__ void gload_lds16(const void* g, void* l) {
    __builtin_amdgcn_global_load_lds((const __attribute__((address_space(1))) void*)g,
                                     (__attribute__((address_space(3))) void*)l, 16, 0, 0);
}

// ---- DPP helpers (full-rate VALU, no LDS pipe) ----
template<int CTRL, int ROWM>
static __device__ __forceinline__ float dppterm(float x) {
    int y = __builtin_amdgcn_update_dpp(0, __float_as_int(x), CTRL, ROWM, 0xf, true);
    return __int_as_float(y);
}
// butterfly reduce within 16-lane rows (all lanes get total)
static __device__ __forceinline__ float rowreduce16(float x) {
    x += dppterm<0xB1, 0xf>(x);    // quad_perm xor1
    x += dppterm<0x4E, 0xf>(x);    // quad_perm xor2
    x += dppterm<0x141, 0xf>(x);   // row_half_mirror (xor4)
    x += dppterm<0x140, 0xf>(x);   // row_mirror (xor8)
    return x;
}
// inclusive scan within 16-lane rows
static __device__ __forceinline__ float scan16(float x) {
    x += dppterm<0x111, 0xf>(x);   // row_shr:1
    x += dppterm<0x112, 0xf>(x);   // row_shr:2
    x += dppterm<0x114, 0xf>(x);   // row_shr:4
    x += dppterm<0x118, 0xf>(x);   // row_shr:8
    return x;
}
// inclusive scan across all 64 lanes
static __device__ __forceinline__ float scan64(float x) {
    x += dppterm<0x111, 0xf>(x);
    x += dppterm<0x112, 0xf>(x);
    x += dppterm<0x114, 0xf>(x);
    x += dppterm<0x118, 0xf>(x);
    x += dppterm<0x142, 0xa>(x);   // row_bcast15 -> rows 1,3
    x += dppterm<0x143, 0xc>(x);   // row_bcast31 -> rows 2,3
    return x;
}

// ---- device-scope grid barrier (sense-reversal, generation-parity counters) ----
// gbar[0], gbar[1] = arrival counters (parity-alternating); gbar[2] = generation.
// Zeroed via hipMemsetAsync before launch. Safe: counter idx is reset before the
// generation release that allows any block to reach the barrier reusing it.
static __device__ __forceinline__ void grid_sync(int* gbar) {
    __syncthreads();
    __threadfence();
    if (threadIdx.x == 0) {
        int gen = __hip_atomic_load(gbar + 2, __ATOMIC_ACQUIRE, __HIP_MEMORY_SCOPE_AGENT);
        int idx = gen & 1;
        int arrived = __hip_atomic_fetch_add(gbar + idx, 1, __ATOMIC_ACQ_REL, __HIP_MEMORY_SCOPE_AGENT) + 1;
        if (arrived == NBLK) {
            __hip_atomic_store(gbar + idx, 0, __ATOMIC_RELAXED, __HIP_MEMORY_SCOPE_AGENT);
            __hip_atomic_store(gbar + 2, gen + 1, __ATOMIC_RELEASE, __HIP_MEMORY_SCOPE_AGENT);
        } else {
            while (__hip_atomic_load(gbar + 2, __ATOMIC_ACQUIRE, __HIP_MEMORY_SCOPE_AGENT) == gen)
                __builtin_amdgcn_s_sleep(1);
        }
    }
    __syncthreads();
    __threadfence();
}

// ---- convert W fp32 -> bf16 (tiny) ----
__global__ void convertW_kernel(const float* __restrict__ W, unsigned short* __restrict__ wb) {
    int t = blockIdx.x * 256 + threadIdx.x;
    float4 v = ((const float4*)W)[t];
    ushort4 o;
    o.x = f2bf(v.x); o.y = f2bf(v.y); o.z = f2bf(v.z); o.w = f2bf(v.w);
    ((ushort4*)wb)[t] = o;
}

// Stage A K-tile (256 rows x 32 cols fp32 = 32 KB) of tile kt into slot.
static __device__ __forceinline__ void stage_Af32(const float* __restrict__ srcBase, char* smem,
                                                  int slot, int kt, int w, int lane) {
#pragma unroll
    for (int j = 0; j < 4; ++j) {
        const float* g = srcBase + (size_t)j * 8 * DIM + kt * BK;
        char* l = smem + (size_t)slot * SLOTB + (w * 4 + j) * 1024 + lane * 16;
        gload_lds16(g, l);
    }
}

// Stage B K-tile (256 rows x 32 cols bf16 = 16 KB) into slot at offset 32KB.
static __device__ __forceinline__ void stage_B16(const unsigned short* __restrict__ srcBase, char* smem,
                                                 int slot, int kt, int w, int lane) {
#pragma unroll
    for (int r = 0; r < 2; ++r) {
        const unsigned short* g = srcBase + (size_t)r * 128 * DIM + kt * BK;
        char* l = smem + (size_t)slot * SLOTB + 32768 + (r * 128 + w * 16) * 64 + lane * 16;
        gload_lds16(g, l);
    }
}

// ---- mega kernel: GEMM (value stays in registers) -> chunk totals -> grid sync
//      -> in-place exclusive scan of totals -> grid sync -> emit out directly ----
__global__ __launch_bounds__(512, 2) void mega_kernel(const float* __restrict__ X,
                                                      const unsigned short* __restrict__ Bm,
                                                      const float* __restrict__ bias,
                                                      const float* __restrict__ ph,
                                                      float* __restrict__ pr,
                                                      float* __restrict__ pi,
                                                      float* __restrict__ out,
                                                      int* __restrict__ gbar) {
    extern __shared__ char smem[];
    const int tid  = threadIdx.x;
    const int lane = tid & 63;
    const int w    = tid >> 6;           // wave 0..7
    const int wm   = w >> 2;             // 0..1
    const int wr   = wm * 128;           // wave row offset (M)
    const int wc   = (w & 3) * 64;       // wave col offset (N)
    const int rl   = lane & 15;
    const int rh   = lane >> 4;
    const int m0   = blockIdx.x * BM;
    const int n0   = blockIdx.y * BN;

    // staging source bases (chunk XOR folded into per-lane global src)
    const float* srcA = X + (size_t)(m0 + w * 32 + (lane >> 3)) * DIM + ((lane & 7) ^ (lane >> 3)) * 4;
    const unsigned short* srcB = Bm + (size_t)(n0 + w * 16 + (lane >> 2)) * DIM
                               + (((lane & 3) ^ ((lane >> 3) & 3)) * 8);

    // read-side offsets
    const int swzB = (rh ^ ((rl >> 1) & 3)) * 16;
    const int aoff0 = (wr + rl) * 128 + (((rh * 2 + 0) ^ (rl & 7)) * 16);
    const int aoff1 = (wr + rl) * 128 + (((rh * 2 + 1) ^ (rl & 7)) * 16);

    f32x4 acc[8][4];
#pragma unroll
    for (int m = 0; m < 8; ++m)
#pragma unroll
        for (int n = 0; n < 4; ++n)
            acc[m][n] = (f32x4){0.f, 0.f, 0.f, 0.f};

    f32x4 bv4[4];
#pragma unroll
    for (int nf = 0; nf < 4; ++nf)
        bv4[nf] = *(const f32x4*)(bias + n0 + wc + nf * 16 + rh * 4);

    // prologue: stage tiles 0 (slot0) and 1 (slot1)
    stage_Af32(srcA, smem, 0, 0, w, lane);
    stage_B16 (srcB, smem, 0, 0, w, lane);
    stage_Af32(srcA, smem, 1, 1, w, lane);
    stage_B16 (srcB, smem, 1, 1, w, lane);

#pragma unroll 1
    for (int t = 0; t < NTK; ++t) {
        asm volatile("s_waitcnt vmcnt(6)" ::: "memory");
        __builtin_amdgcn_s_barrier();
        const int sc = t % 3;
        const int ss = (t + 2) % 3;
        const int kn = (t + 2) & (NTK - 1);
        const char* sb = smem + (size_t)sc * SLOTB;

        bf16x8 bfr[4];
#pragma unroll
        for (int nf = 0; nf < 4; ++nf)
            bfr[nf] = *(const bf16x8*)(sb + 32768 + (wc + nf * 16 + rl) * 64 + swzB);

        bf16x8 af[4];
#pragma unroll
        for (int mf = 0; mf < 4; ++mf) {
            f32x4 q0 = *(const f32x4*)(sb + mf * 2048 + aoff0);
            f32x4 q1 = *(const f32x4*)(sb + mf * 2048 + aoff1);
            union { unsigned u[4]; bf16x8 v; } cv;
            cv.u[0] = cvtpk(q0[0], q0[1]); cv.u[1] = cvtpk(q0[2], q0[3]);
            cv.u[2] = cvtpk(q1[0], q1[1]); cv.u[3] = cvtpk(q1[2], q1[3]);
            af[mf] = cv.v;
        }
        stage_Af32(srcA, smem, ss, kn, w, lane);
        __builtin_amdgcn_s_setprio(1);
#pragma unroll
        for (int mf = 0; mf < 4; ++mf)
#pragma unroll
            for (int nf = 0; nf < 4; ++nf)
                acc[mf][nf] = __builtin_amdgcn_mfma_f32_16x16x32_bf16(bfr[nf], af[mf], acc[mf][nf], 0, 0, 0);
        __builtin_amdgcn_s_setprio(0);

#pragma unroll
        for (int mf = 0; mf < 4; ++mf) {
            f32x4 q0 = *(const f32x4*)(sb + (mf + 4) * 2048 + aoff0);
            f32x4 q1 = *(const f32x4*)(sb + (mf + 4) * 2048 + aoff1);
            union { unsigned u[4]; bf16x8 v; } cv;
            cv.u[0] = cvtpk(q0[0], q0[1]); cv.u[1] = cvtpk(q0[2], q0[3]);
            cv.u[2] = cvtpk(q1[0], q1[1]); cv.u[3] = cvtpk(q1[2], q1[3]);
            af[mf] = cv.v;
        }
        stage_B16(srcB, smem, ss, kn, w, lane);
        __builtin_amdgcn_s_setprio(1);
#pragma unroll
        for (int mf = 0; mf < 4; ++mf)
#pragma unroll
            for (int nf = 0; nf < 4; ++nf)
                acc[mf + 4][nf] = __builtin_amdgcn_mfma_f32_16x16x32_bf16(bfr[nf], af[mf], acc[mf + 4][nf], 0, 0, 0);
        __builtin_amdgcn_s_setprio(0);
    }

    // fold bias into acc (value now final, lives in registers through phase 4)
#pragma unroll
    for (int mf = 0; mf < 8; ++mf)
#pragma unroll
        for (int nf = 0; nf < 4; ++nf)
#pragma unroll
            for (int j = 0; j < 4; ++j)
                acc[mf][nf][j] += bv4[nf][j];

    const int bb    = m0 >> 12;              // batch
    const int lbase = m0 & (SEQ - 1);        // first in-batch row of block
    const int lb    = lbase + wr;            // first in-batch row of this wave

    // ==== phase 2: per-chunk totals -> pr/pi (single writer per (b,c,e)) ====
    {
        float csr[2][4][4], csi[2][4][4];
#pragma unroll
        for (int h = 0; h < 2; ++h)
#pragma unroll
            for (int nf = 0; nf < 4; ++nf)
#pragma unroll
                for (int j = 0; j < 4; ++j) { csr[h][nf][j] = 0.f; csi[h][nf][j] = 0.f; }
#pragma unroll
        for (int mf = 0; mf < 8; ++mf) {
            const int l = lb + mf * 16 + rl;
            const int half = mf >> 2;
#pragma unroll
            for (int nf = 0; nf < 4; ++nf) {
                const int gcol0 = n0 + wc + nf * 16 + rh * 4;
                f32x4 pp = *(const f32x4*)(ph + (size_t)l * DIM + gcol0);
#pragma unroll
                for (int j = 0; j < 4; ++j) {
                    float s, cn;
                    __sincosf(pp[j], &s, &cn);
                    csr[half][nf][j] += acc[mf][nf][j] * cn;
                    csi[half][nf][j] += acc[mf][nf][j] * s;
                }
            }
        }
#pragma unroll
        for (int h = 0; h < 2; ++h)
#pragma unroll
            for (int nf = 0; nf < 4; ++nf)
#pragma unroll
                for (int j = 0; j < 4; ++j) {
                    csr[h][nf][j] = rowreduce16(csr[h][nf][j]);
                    csi[h][nf][j] = rowreduce16(csi[h][nf][j]);
                }
        if (rl == 0) {
#pragma unroll
            for (int h = 0; h < 2; ++h) {
                const int c = (lb >> 6) + h;
                const size_t base = ((size_t)bb * NC + c) * DIM;
#pragma unroll
                for (int nf = 0; nf < 4; ++nf) {
                    const int gcol0 = n0 + wc + nf * 16 + rh * 4;
                    *(float4*)(pr + base + gcol0) =
                        (float4){csr[h][nf][0], csr[h][nf][1], csr[h][nf][2], csr[h][nf][3]};
                    *(float4*)(pi + base + gcol0) =
                        (float4){csi[h][nf][0], csi[h][nf][1], csi[h][nf][2], csi[h][nf][3]};
                }
            }
        }
    }

    grid_sync(gbar);

    // ==== phase 3: totals -> exclusive prefixes, in place. 4096 (b,e) tasks,
    //      2 per wave, lane = chunk (64 lanes = 64 chunks) ====
    {
        const int bid = blockIdx.y * 64 + blockIdx.x;
        const int wid = bid * 8 + w;
#pragma unroll
        for (int s = 0; s < 2; ++s) {
            const int task = wid * 2 + s;
            const int b = task >> 10;
            const int e = task & 1023;
            const size_t idx = (size_t)(b * NC + lane) * DIM + e;
            float r  = pr[idx];
            float im = pi[idx];
            pr[idx] = scan64(r) - r;     // exclusive = inclusive - self
            pi[idx] = scan64(im) - im;
        }
    }

    grid_sync(gbar);

    // ==== phase 4: emit out directly from registers ====
    float rns[2][4];
#pragma unroll
    for (int h = 0; h < 2; ++h)
#pragma unroll
        for (int q = 0; q < 4; ++q)
            rns[h][q] = rsqrtf((float)(lb + h * 64 + q * 16 + rl + 1));

#pragma unroll
    for (int h = 0; h < 2; ++h) {
        const int c = (lb >> 6) + h;
        const size_t pbase = ((size_t)bb * NC + c) * DIM;
#pragma unroll
        for (int nf = 0; nf < 4; ++nf) {
            const int gcol0 = n0 + wc + nf * 16 + rh * 4;
            f32x4 preR = *(const f32x4*)(pr + pbase + gcol0);
            f32x4 preI = *(const f32x4*)(pi + pbase + gcol0);
            float sn[4][4], cs[4][4];
#pragma unroll
            for (int q = 0; q < 4; ++q) {
                const int l = lb + h * 64 + q * 16 + rl;
                f32x4 pp = *(const f32x4*)(ph + (size_t)l * DIM + gcol0);
#pragma unroll
                for (int j = 0; j < 4; ++j)
                    __sincosf(pp[j], &sn[q][j], &cs[q][j]);
            }
            float ov[4][4];
#pragma unroll
            for (int j = 0; j < 4; ++j) {
                float cR = preR[j];
                float cI = preI[j];
#pragma unroll
                for (int q = 0; q < 4; ++q) {
                    float v  = acc[h * 4 + q][nf][j];
                    float vR = v * cs[q][j];
                    float vI = v * sn[q][j];
                    float cumR = scan16(vR) + cR;   // seq order within chunk = q*16+rl
                    float cumI = scan16(vI) + cI;
                    ov[q][j] = (cumR * cs[q][j] + cumI * sn[q][j]) * rns[h][q];
                    if (q < 3) { cR += rowreduce16(vR); cI += rowreduce16(vI); }
                }
            }
#pragma unroll
            for (int q = 0; q < 4; ++q) {
                const int l = lb + h * 64 + q * 16 + rl;
                *(float4*)(out + ((size_t)bb * SEQ + l) * DIM + gcol0) =
                    (float4){ov[q][0], ov[q][1], ov[q][2], ov[q][3]};
            }
        }
    }
}

extern "C" void kernel_launch(void* const* d_in, const int* in_sizes, int n_in,
                              void* d_out, int out_size, void* d_ws, size_t ws_size,
                              hipStream_t stream) {
    const float* x  = (const float*)d_in[0];
    const float* ph = (const float*)d_in[1];
    const float* W  = (const float*)d_in[2];
    const float* b  = (const float*)d_in[3];
    float* out = (float*)d_out;

    // ws: wb 2MB | pr 1MB | pi 1MB | gbar 12B
    unsigned short* wb = (unsigned short*)d_ws;
    float* pr = (float*)(wb + (size_t)DIM * DIM);
    float* pi = pr + (size_t)NB * NC * DIM;
    int* gbar = (int*)(pi + (size_t)NB * NC * DIM);

    (void)hipFuncSetAttribute((const void*)mega_kernel,
                              hipFuncAttributeMaxDynamicSharedMemorySize, GEMM_LDS);

    // 0) zero grid-barrier state (deterministic per launch)
    hipMemsetAsync(gbar, 0, 3 * sizeof(int), stream);
    // 1) convert W (x-conversion fused into GEMM LDS pipeline)
    convertW_kernel<<<DIM * DIM / 4 / 256, 256, 0, stream>>>(W, wb);
    // 2) mega kernel: GEMM + chunk totals + grid-scan + emit (value never hits HBM)
    {
        dim3 grid(MROWS / BM, DIM / BN);   // 64 x 4 = 256 blocks = 1/CU (144KB LDS)
        mega_kernel<<<grid, 512, GEMM_LDS, stream>>>(x, wb, b, ph, pr, pi, out, gbar);
    }
}

// Round 15
// 84.897 us; speedup vs baseline: 3.4685x; 3.4685x over previous
//
#include <hip/hip_runtime.h>
#include <hip/hip_bf16.h>

#define DIM 1024
#define SEQ 4096
#define NB 4
#define MROWS (NB * SEQ)   // 16384
#define NC 64              // chunks per sequence
#define CL (SEQ / NC)      // 64 L-positions per chunk

// GEMM tiling: 256x256 tile, BK=32, 3 LDS slots (A fp32 32KB + B bf16 16KB each)
#define BM 256
#define BN 256
#define BK 32
#define NTK 32                   // K-tiles: 1024/32
#define SLOTB 49152              // 48 KB per slot
#define GEMM_LDS (3 * SLOTB)     // 144 KB

typedef __attribute__((ext_vector_type(8))) short bf16x8;
typedef __attribute__((ext_vector_type(4))) float f32x4;

static __device__ __forceinline__ unsigned short f2bf(float f) {
    union { float f; unsigned u; } v; v.f = f;
    unsigned r = v.u + 0x7FFF + ((v.u >> 16) & 1);
    return (unsigned short)(r >> 16);
}

static __device__ __forceinline__ float bf2f(unsigned short h) {
    union { unsigned u; float f; } v; v.u = ((unsigned)h) << 16;
    return v.f;
}

// v_cvt_pk_bf16_f32: RNE, lo=bf16(a), hi=bf16(b)
static __device__ __forceinline__ unsigned cvtpk(float a, float b) {
    unsigned r;
    asm("v_cvt_pk_bf16_f32 %0, %1, %2" : "=v"(r) : "v"(a), "v"(b));
    return r;
}

static __device__ __forceinline__ void gload_lds16(const void* g, void* l) {
    __builtin_amdgcn_global_load_lds((const __attribute__((address_space(1))) void*)g,
                                     (__attribute__((address_space(3))) void*)l, 16, 0, 0);
}

// DPP butterfly add over 16-lane rows (full-rate VALU, no LDS pipe)
template<int CTRL>
static __device__ __forceinline__ float dppadd(float x) {
    int y = __builtin_amdgcn_update_dpp(0, __float_as_int(x), CTRL, 0xf, 0xf, true);
    return x + __int_as_float(y);
}
static __device__ __forceinline__ float rowreduce16(float x) {
    x = dppadd<0xB1>(x);    // xor1
    x = dppadd<0x4E>(x);    // xor2
    x = dppadd<0x141>(x);   // xor4 (row_half_mirror)
    x = dppadd<0x140>(x);   // xor8 (row_mirror)
    return x;
}

// ---- convert W fp32 -> bf16 (tiny) ----
__global__ void convertW_kernel(const float* __restrict__ W, unsigned short* __restrict__ wb) {
    int t = blockIdx.x * 256 + threadIdx.x;
    float4 v = ((const float4*)W)[t];
    ushort4 o;
    o.x = f2bf(v.x); o.y = f2bf(v.y); o.z = f2bf(v.z); o.w = f2bf(v.w);
    ((ushort4*)wb)[t] = o;
}

// Stage A K-tile (256 rows x 32 cols fp32 = 32 KB) of tile kt into slot.
// LDS rows 128B = 8 chunks of 16B, stored slot s holds global chunk s^(row&7).
static __device__ __forceinline__ void stage_Af32(const float* __restrict__ srcBase, char* smem,
                                                  int slot, int kt, int w, int lane) {
#pragma unroll
    for (int j = 0; j < 4; ++j) {
        const float* g = srcBase + (size_t)j * 8 * DIM + kt * BK;
        char* l = smem + (size_t)slot * SLOTB + (w * 4 + j) * 1024 + lane * 16;
        gload_lds16(g, l);
    }
}

// Stage B K-tile (256 rows x 32 cols bf16 = 16 KB) into slot at offset 32KB.
static __device__ __forceinline__ void stage_B16(const unsigned short* __restrict__ srcBase, char* smem,
                                                 int slot, int kt, int w, int lane) {
#pragma unroll
    for (int r = 0; r < 2; ++r) {
        const unsigned short* g = srcBase + (size_t)r * 128 * DIM + kt * BK;
        char* l = smem + (size_t)slot * SLOTB + 32768 + (r * 128 + w * 16) * 64 + lane * 16;
        gload_lds16(g, l);
    }
}

// ---- GEMM + fused passA: V = bf16(X@W^T + b); pr/pi[b][c][e] = per-chunk sums ----
__global__ __launch_bounds__(512, 2) void gemm_kernel(const float* __restrict__ X,
                                                      const unsigned short* __restrict__ Bm,
                                                      const float* __restrict__ bias,
                                                      const float* __restrict__ ph,
                                                      unsigned short* __restrict__ V,
                                                      float* __restrict__ pr,
                                                      float* __restrict__ pi) {
    extern __shared__ char smem[];
    const int tid  = threadIdx.x;
    const int lane = tid & 63;
    const int w    = tid >> 6;           // wave 0..7
    const int wr   = (w >> 2) * 128;     // wave row offset (M)
    const int wc   = (w & 3) * 64;       // wave col offset (N)
    const int rl   = lane & 15;
    const int rh   = lane >> 4;
    const int m0   = blockIdx.x * BM;
    const int n0   = blockIdx.y * BN;

    // staging source bases (chunk XOR folded into per-lane global src)
    const float* srcA = X + (size_t)(m0 + w * 32 + (lane >> 3)) * DIM + ((lane & 7) ^ (lane >> 3)) * 4;
    const unsigned short* srcB = Bm + (size_t)(n0 + w * 16 + (lane >> 2)) * DIM
                               + (((lane & 3) ^ ((lane >> 3) & 3)) * 8);

    // read-side offsets
    const int swzB = (rh ^ ((rl >> 1) & 3)) * 16;
    const int aoff0 = (wr + rl) * 128 + (((rh * 2 + 0) ^ (rl & 7)) * 16);
    const int aoff1 = (wr + rl) * 128 + (((rh * 2 + 1) ^ (rl & 7)) * 16);

    f32x4 acc[8][4];
#pragma unroll
    for (int m = 0; m < 8; ++m)
#pragma unroll
        for (int n = 0; n < 4; ++n)
            acc[m][n] = (f32x4){0.f, 0.f, 0.f, 0.f};

    f32x4 bv4[4];
#pragma unroll
    for (int nf = 0; nf < 4; ++nf)
        bv4[nf] = *(const f32x4*)(bias + n0 + wc + nf * 16 + rh * 4);

    // prologue: stage tiles 0 (slot0) and 1 (slot1)
    stage_Af32(srcA, smem, 0, 0, w, lane);
    stage_B16 (srcB, smem, 0, 0, w, lane);
    stage_Af32(srcA, smem, 1, 1, w, lane);
    stage_B16 (srcB, smem, 1, 1, w, lane);

#pragma unroll 1
    for (int t = 0; t < NTK; ++t) {
        asm volatile("s_waitcnt vmcnt(6)" ::: "memory");
        __builtin_amdgcn_s_barrier();
        const int sc = t % 3;
        const int ss = (t + 2) % 3;
        const int kn = (t + 2) & (NTK - 1);
        const char* sb = smem + (size_t)sc * SLOTB;

        bf16x8 bfr[4];
#pragma unroll
        for (int nf = 0; nf < 4; ++nf)
            bfr[nf] = *(const bf16x8*)(sb + 32768 + (wc + nf * 16 + rl) * 64 + swzB);

        bf16x8 af[4];
#pragma unroll
        for (int mf = 0; mf < 4; ++mf) {
            f32x4 q0 = *(const f32x4*)(sb + mf * 2048 + aoff0);
            f32x4 q1 = *(const f32x4*)(sb + mf * 2048 + aoff1);
            union { unsigned u[4]; bf16x8 v; } cv;
            cv.u[0] = cvtpk(q0[0], q0[1]); cv.u[1] = cvtpk(q0[2], q0[3]);
            cv.u[2] = cvtpk(q1[0], q1[1]); cv.u[3] = cvtpk(q1[2], q1[3]);
            af[mf] = cv.v;
        }
        stage_Af32(srcA, smem, ss, kn, w, lane);
        __builtin_amdgcn_s_setprio(1);
#pragma unroll
        for (int mf = 0; mf < 4; ++mf)
#pragma unroll
            for (int nf = 0; nf < 4; ++nf)
                acc[mf][nf] = __builtin_amdgcn_mfma_f32_16x16x32_bf16(bfr[nf], af[mf], acc[mf][nf], 0, 0, 0);
        __builtin_amdgcn_s_setprio(0);

#pragma unroll
        for (int mf = 0; mf < 4; ++mf) {
            f32x4 q0 = *(const f32x4*)(sb + (mf + 4) * 2048 + aoff0);
            f32x4 q1 = *(const f32x4*)(sb + (mf + 4) * 2048 + aoff1);
            union { unsigned u[4]; bf16x8 v; } cv;
            cv.u[0] = cvtpk(q0[0], q0[1]); cv.u[1] = cvtpk(q0[2], q0[3]);
            cv.u[2] = cvtpk(q1[0], q1[1]); cv.u[3] = cvtpk(q1[2], q1[3]);
            af[mf] = cv.v;
        }
        stage_B16(srcB, smem, ss, kn, w, lane);
        __builtin_amdgcn_s_setprio(1);
#pragma unroll
        for (int mf = 0; mf < 4; ++mf)
#pragma unroll
            for (int nf = 0; nf < 4; ++nf)
                acc[mf + 4][nf] = __builtin_amdgcn_mfma_f32_16x16x32_bf16(bfr[nf], af[mf], acc[mf + 4][nf], 0, 0, 0);
        __builtin_amdgcn_s_setprio(0);
    }

    // ==== epilogue: value store + fused per-chunk phasor sums ====
    const int bb = m0 >> 12;                 // batch (4096 rows/batch)
    const int lb = (m0 & (SEQ - 1)) + wr;    // first in-batch row of this wave-half
    float csr[2][4][4], csi[2][4][4];
#pragma unroll
    for (int h = 0; h < 2; ++h)
#pragma unroll
        for (int nf = 0; nf < 4; ++nf)
#pragma unroll
            for (int j = 0; j < 4; ++j) { csr[h][nf][j] = 0.f; csi[h][nf][j] = 0.f; }

#pragma unroll
    for (int mf = 0; mf < 8; ++mf) {
        const int l    = lb + mf * 16 + rl;          // in-batch seq position
        const int grow = m0 + wr + mf * 16 + rl;
        const int half = mf >> 2;
#pragma unroll
        for (int nf = 0; nf < 4; ++nf) {
            const int gcol0 = n0 + wc + nf * 16 + rh * 4;
            f32x4 pp = *(const f32x4*)(ph + (size_t)l * DIM + gcol0);
            unsigned short os[4];
#pragma unroll
            for (int j = 0; j < 4; ++j) {
                float v = acc[mf][nf][j] + bv4[nf][j];
                float s, cn;
                __sincosf(pp[j], &s, &cn);
                csr[half][nf][j] += v * cn;
                csi[half][nf][j] += v * s;
                os[j] = f2bf(v);
            }
            ushort4 o; o.x = os[0]; o.y = os[1]; o.z = os[2]; o.w = os[3];
            *(ushort4*)(V + (size_t)grow * DIM + gcol0) = o;
        }
    }
    // reduce over rl (16-lane DPP rows; rh groups ARE the DPP rows)
#pragma unroll
    for (int h = 0; h < 2; ++h)
#pragma unroll
        for (int nf = 0; nf < 4; ++nf)
#pragma unroll
            for (int j = 0; j < 4; ++j) {
                csr[h][nf][j] = rowreduce16(csr[h][nf][j]);
                csi[h][nf][j] = rowreduce16(csi[h][nf][j]);
            }
    if (rl == 0) {
#pragma unroll
        for (int h = 0; h < 2; ++h) {
            const int c = (lb + h * 64) >> 6;        // chunk within batch
            const size_t base = ((size_t)bb * NC + c) * DIM;
#pragma unroll
            for (int nf = 0; nf < 4; ++nf) {
                const int gcol0 = n0 + wc + nf * 16 + rh * 4;
                *(float4*)(pr + base + gcol0) =
                    (float4){csr[h][nf][0], csr[h][nf][1], csr[h][nf][2], csr[h][nf][3]};
                *(float4*)(pi + base + gcol0) =
                    (float4){csi[h][nf][0], csi[h][nf][1], csi[h][nf][2], csi[h][nf][3]};
            }
        }
    }
}

// ---- pass B: exclusive scan of chunk partials over c ----
__global__ void passB_kernel(float* __restrict__ pr, float* __restrict__ pi) {
    int t = blockIdx.x * 256 + threadIdx.x;
    int bb = t >> 10;
    int e  = t & 1023;
    float r = 0.f, im = 0.f;
    for (int c = 0; c < NC; ++c) {
        size_t idx = ((size_t)bb * NC + c) * DIM + e;
        float tr = pr[idx], ti = pi[idx];
        pr[idx] = r; pi[idx] = im;
        r += tr; im += ti;
    }
}

// ---- pass C: running cumsum + retrieval + norm -> fp32 out ----
__global__ void passC_kernel(const unsigned short* __restrict__ val, const float* __restrict__ ph,
                             const float* __restrict__ pr, const float* __restrict__ pi,
                             float* __restrict__ out) {
    int t  = blockIdx.x * 256 + threadIdx.x;
    int c  = blockIdx.y;
    int bb = blockIdx.z;
    size_t base = ((size_t)bb * SEQ + (size_t)c * CL) * (DIM / 2) + t;
    const ushort2* v = (const ushort2*)val + base;
    const float2*  p = (const float2*)ph + (size_t)c * CL * (DIM / 2) + t;
    float2* o = (float2*)out + base;
    size_t pidx = ((size_t)bb * NC + c) * DIM + 2 * t;
    float ar0 = pr[pidx], ar1 = pr[pidx + 1];
    float ai0 = pi[pidx], ai1 = pi[pidx + 1];
    const int l0 = c * CL;
    for (int l = 0; l < CL; ++l) {
        ushort2 vv = v[(size_t)l * (DIM / 2)];
        float2  pp = p[(size_t)l * (DIM / 2)];
        float v0 = bf2f(vv.x), v1 = bf2f(vv.y);
        float s0, c0, s1, c1;
        __sincosf(pp.x, &s0, &c0);
        __sincosf(pp.y, &s1, &c1);
        ar0 += v0 * c0; ai0 += v0 * s0;
        ar1 += v1 * c1; ai1 += v1 * s1;
        float rn = rsqrtf((float)(l0 + l + 1));
        float2 ov;
        ov.x = (ar0 * c0 + ai0 * s0) * rn;
        ov.y = (ar1 * c1 + ai1 * s1) * rn;
        o[(size_t)l * (DIM / 2)] = ov;
    }
}

extern "C" void kernel_launch(void* const* d_in, const int* in_sizes, int n_in,
                              void* d_out, int out_size, void* d_ws, size_t ws_size,
                              hipStream_t stream) {
    const float* x  = (const float*)d_in[0];
    const float* ph = (const float*)d_in[1];
    const float* W  = (const float*)d_in[2];
    const float* b  = (const float*)d_in[3];
    float* out = (float*)d_out;

    // ws: vb bf16 32MB | wb 2MB | pr 1MB | pi 1MB
    unsigned short* vb = (unsigned short*)d_ws;
    unsigned short* wb = vb + (size_t)MROWS * DIM;
    float* pr = (float*)(wb + (size_t)DIM * DIM);
    float* pi = pr + (size_t)NB * NC * DIM;

    (void)hipFuncSetAttribute((const void*)gemm_kernel,
                              hipFuncAttributeMaxDynamicSharedMemorySize, GEMM_LDS);

    // 1) convert W only (x-conversion fused into GEMM LDS pipeline)
    convertW_kernel<<<DIM * DIM / 4 / 256, 256, 0, stream>>>(W, wb);
    // 2) GEMM + fused chunk-sum pass -> vb, pr, pi
    {
        dim3 grid(MROWS / BM, DIM / BN);
        gemm_kernel<<<grid, 512, GEMM_LDS, stream>>>(x, wb, b, ph, vb, pr, pi);
    }
    // 3) scan partials
    passB_kernel<<<16, 256, 0, stream>>>(pr, pi);
    // 4) final cumsum + retrieve + norm -> fp32 d_out
    {
        dim3 grid(DIM / 512, NC, NB);
        passC_kernel<<<grid, 256, 0, stream>>>(vb, ph, pr, pi, out);
    }
}